// Round 1
// baseline (66.382 us; speedup 1.0000x reference)
//
#include <hip/hip_runtime.h>
#include <hip/hip_bf16.h>

#define MARGIN 1.0f
#define C_DIM 1024

// ---------------------------------------------------------------------------
// Kernel 1: detect the storage width of the boolean pos_mask buffer.
// The harness may hand us bool as 1-byte (raw numpy bool), int32, or even a
// float-ish dtype. We scan the first n 32-bit words and collect evidence bits:
//   bit0: some byte == 1 at byte-offset > 0            -> uint8 layout
//   bit1: some halfword == 0x3F80 (bf16 1.0) or 0x3C00 (fp16 1.0) -> 2-byte
//   bit2: some word == 0x3F800000 (fp32 1.0)           -> 4-byte float
// No evidence -> int32 {0,1} layout (also 4-byte nonzero test).
// ---------------------------------------------------------------------------
__global__ void detect_mask_fmt(const unsigned int* __restrict__ w, int n,
                                unsigned int* __restrict__ flag) {
    unsigned int ev = 0u;
    for (int i = blockIdx.x * blockDim.x + threadIdx.x; i < n;
         i += gridDim.x * blockDim.x) {
        unsigned int x = w[i];
        if (x == 0u) continue;
        if (x == 0x3F800000u) ev |= 4u;
        unsigned int h0 = x & 0xFFFFu, h1 = x >> 16;
        if (h0 == 0x3F80u || h1 == 0x3F80u || h0 == 0x3C00u || h1 == 0x3C00u)
            ev |= 2u;
        unsigned int b1 = (x >> 8) & 0xFFu, b2 = (x >> 16) & 0xFFu,
                     b3 = (x >> 24) & 0xFFu;
        if (b1 == 1u || b2 == 1u || b3 == 1u) ev |= 1u;
    }
    if (ev) atomicOr(flag, ev);
}

// ---------------------------------------------------------------------------
// Kernel 2: one block per row. Stage scores + mask in LDS, compact the
// positive scores, then each thread strides over negatives with an inner
// loop over the (few) positives. Block-reduce, one atomicAdd per block into
// acc[0]=loss_sum, acc[1]=denom_sum.
// ---------------------------------------------------------------------------
__global__ __launch_bounds__(256) void row_loss(
    const float* __restrict__ scores, const void* __restrict__ mask,
    const unsigned int* __restrict__ flag, float* __restrict__ acc) {
    __shared__ float s[C_DIM];
    __shared__ float ps[C_DIM];          // compacted positive scores
    __shared__ unsigned char pf[C_DIM];  // is-positive flag
    __shared__ int npos_sh;
    __shared__ float wsum[4];

    const int row = blockIdx.x;
    const int tid = threadIdx.x;
    if (tid == 0) npos_sh = 0;
    __syncthreads();

    const unsigned int f = *flag;  // wave-uniform
    const int width = (f & 4u) ? 4 : (f & 2u) ? 2 : (f & 1u) ? 1 : 4;
    const int base = row * C_DIM;

    for (int i = tid; i < C_DIM; i += 256) {
        s[i] = scores[base + i];
        bool p;
        if (width == 4)      p = ((const unsigned int*)mask)[base + i] != 0u;
        else if (width == 2) p = ((const unsigned short*)mask)[base + i] != 0;
        else                 p = ((const unsigned char*)mask)[base + i] != 0;
        pf[i] = p ? 1 : 0;
    }
    __syncthreads();

    for (int i = tid; i < C_DIM; i += 256) {
        if (pf[i]) {
            int k = atomicAdd(&npos_sh, 1);
            ps[k] = s[i];
        }
    }
    __syncthreads();

    const int np = npos_sh;
    float local = 0.0f;
    for (int i = tid; i < C_DIM; i += 256) {
        if (!pf[i]) {
            const float sn = s[i] + MARGIN;
            for (int j = 0; j < np; ++j) {
                const float d = sn - ps[j];
                local += fmaxf(d, 0.0f);
            }
        }
    }

    // 64-lane wave reduce, then across the 4 waves via LDS.
    for (int off = 32; off > 0; off >>= 1) local += __shfl_down(local, off);
    const int lane = tid & 63, wave = tid >> 6;
    if (lane == 0) wsum[wave] = local;
    __syncthreads();
    if (tid == 0) {
        const float tot = wsum[0] + wsum[1] + wsum[2] + wsum[3];
        atomicAdd(&acc[0], tot);
        atomicAdd(&acc[1], (float)np * (float)(C_DIM - np));
    }
}

// ---------------------------------------------------------------------------
// Kernel 3: finalize the scalar.
// ---------------------------------------------------------------------------
__global__ void finalize(const float* __restrict__ acc,
                         float* __restrict__ out) {
    const float d = acc[1];
    out[0] = (d == 0.0f) ? 0.0f : acc[0] / d;
}

extern "C" void kernel_launch(void* const* d_in, const int* in_sizes, int n_in,
                              void* d_out, int out_size, void* d_ws,
                              size_t ws_size, hipStream_t stream) {
    const float* scores = (const float*)d_in[0];
    const void* mask = d_in[1];

    const int total = in_sizes[0];
    const int B = total / C_DIM;  // 128 for the reference shape

    float* acc = (float*)d_ws;                       // acc[0]=loss, acc[1]=denom
    unsigned int* flag = (unsigned int*)d_ws + 2;    // mask-format evidence

    hipMemsetAsync(d_ws, 0, 16, stream);

    const int nwords = in_sizes[1] / 4;
    detect_mask_fmt<<<64, 256, 0, stream>>>((const unsigned int*)mask, nwords,
                                            flag);
    row_loss<<<B, 256, 0, stream>>>(scores, mask, flag, acc);
    finalize<<<1, 1, 0, stream>>>(acc, (float*)d_out);
}